// Round 1
// 2427.368 us; speedup vs baseline: 1.5839x; 1.5839x over previous
//
#include <hip/hip_runtime.h>
#include <hip/hip_bf16.h>
#include <math.h>

typedef __hip_bfloat16 bf16;
typedef short s16x8 __attribute__((ext_vector_type(8)));
typedef float f32x4 __attribute__((ext_vector_type(4)));

#define NN 50000
#define EE 150000
#define EH 75000   // linkpred edge-chunk (2 halves) so t1 fits workspace

static __device__ __forceinline__ float b2f(bf16 x){ return __bfloat162float(x); }
static __device__ __forceinline__ bf16 f2b(float x){ return __float2bfloat16(x); }
static __device__ __forceinline__ short f2s(float x){
  union { bf16 b; short s; } u; u.b = f2b(x); return u.s;
}
static __device__ __forceinline__ float u2f_lo(unsigned u){ union{unsigned i;float f;}c; c.i=u<<16; return c.f; }
static __device__ __forceinline__ float u2f_hi(unsigned u){ union{unsigned i;float f;}c; c.i=u&0xffff0000u; return c.f; }

// async global->LDS, 16B per lane. LDS dest is wave-uniform base + lane*16;
// global source address is per-lane (carries gather + swizzle).
static __device__ __forceinline__ void gload_lds16(const void* g, void* l){
  __builtin_amdgcn_global_load_lds((const __attribute__((address_space(1))) void*)g,
                                   (__attribute__((address_space(3))) void*)l, 16, 0, 0);
}

// ---------------- utility ----------------
__global__ void k_zero(int* __restrict__ p, int n){
  int i = blockIdx.x*blockDim.x + threadIdx.x;
  if(i<n) p[i]=0;
}

// ---------------- CSR build ----------------
__global__ void k_hist(const int* __restrict__ dst, int* __restrict__ deg){
  int i = blockIdx.x*blockDim.x + threadIdx.x;
  if(i<EE) atomicAdd(&deg[dst[i]], 1);
}

__global__ void k_scan(const int* __restrict__ deg, int* __restrict__ rowptr){
  __shared__ int part[1024];
  int tid = threadIdx.x;
  const int n = NN;
  int chunk = (n + 1023)/1024;
  int start = tid*chunk;
  int end = start + chunk; if(end > n) end = n;
  int s = 0;
  for(int i=start;i<end;i++) s += deg[i];
  part[tid] = s; __syncthreads();
  for(int off=1; off<1024; off<<=1){
    int v = (tid>=off)? part[tid-off] : 0;
    __syncthreads();
    part[tid] += v;
    __syncthreads();
  }
  int run = (tid==0)? 0 : part[tid-1];
  for(int i=start;i<end;i++){ rowptr[i]=run; run += deg[i]; }
  if(tid==0) rowptr[n] = part[1023];
}

__global__ void k_scatter(const int* __restrict__ dst, const int* __restrict__ rowptr,
                          int* __restrict__ cursor, int* __restrict__ elist){
  int e = blockIdx.x*blockDim.x + threadIdx.x;
  if(e<EE){ int d=dst[e]; int p=atomicAdd(&cursor[d],1); elist[rowptr[d]+p]=e; }
}

// ------- time encoding -> relpad [E,112] (cols 100..111 zero) -------
__global__ void k_relenc(const int* __restrict__ src, const int* __restrict__ tt,
                         const int* __restrict__ lu, const float* __restrict__ tw,
                         const float* __restrict__ tb, bf16* __restrict__ rel){
  int i = blockIdx.x*blockDim.x + threadIdx.x;
  if(i >= EE*112) return;
  int e = i/112, c = i - e*112;
  float v = 0.f;
  if(c < 100){
    float rt  = (float)(lu[src[e]] - tt[e]);
    float arg = __fadd_rn(__fmul_rn(rt, tw[c]), tb[c]);
    v = cosf(arg);
  }
  rel[i] = f2b(v);
}

// ------- generic weight transpose: WT[n][k] = W[k][colofs+n], bf16, zero-pad --------
__global__ void k_wt2(const float* __restrict__ W, int K, int N, int colofs, int ncols,
                      bf16* __restrict__ WT, int kpad, int nrows){
  int i = blockIdx.x*blockDim.x + threadIdx.x;
  if(i >= nrows*kpad) return;
  int n = i / kpad, k = i - n*kpad;
  float v = (n<ncols && k<K)? W[(size_t)k*N + colofs + n] : 0.f;
  WT[i] = f2b(v);
}

// ------- conv1 stacked weights: 8 heads x [448 rows: q|k|v|s|pad][128] ---------------
__global__ void k_wtc1(const float* __restrict__ qw, const float* __restrict__ kw,
                       const float* __restrict__ vw, const float* __restrict__ sw,
                       bf16* __restrict__ outp){
  int i = blockIdx.x*blockDim.x + threadIdx.x;
  if(i >= 8*448*128) return;
  int h = i/(448*128), r = (i/128)%448, k = i&127;
  float v = 0.f;
  if(r < 400 && k < 100){
    int s = r/100, n = r - s*100;
    const float* W = s==0? qw : s==1? kw : s==2? vw : sw;
    v = W[(size_t)k*800 + h*100 + n];
  }
  outp[i] = f2b(v);
}

// ------- edge weights [112][256]: k<100 -> rel rows, 128..227 -> msg rows (shifted) ---
__global__ void k_wte(const float* __restrict__ ew, int N, int colofs,
                      bf16* __restrict__ outp){
  int i = blockIdx.x*blockDim.x + threadIdx.x;
  if(i >= 112*256) return;
  int r = i>>8, k = i&255;
  float v = 0.f;
  if(r < 100){
    if(k < 100) v = ew[(size_t)k*N + colofs + r];
    else if(k >= 128 && k < 228) v = ew[(size_t)(k-28)*N + colofs + r];
  }
  outp[i] = f2b(v);
}

// ------- stacked bias ----------------
__global__ void k_bstack(const float* __restrict__ b0, const float* __restrict__ b1,
                         const float* __restrict__ b2, const float* __restrict__ b3,
                         int W, int H, float* __restrict__ outp){
  int i = blockIdx.x*blockDim.x + threadIdx.x;
  if(i >= H*4*W) return;
  int h = i/(4*W), r = i - h*4*W, s = r/W, c = r - s*W;
  const float* b = s==0? b0 : s==1? b1 : s==2? b2 : b3;
  outp[i] = b[h*W + c];
}

// ---------------- LDS-staged tiled MFMA GEMM (m97-style) ----------------
// BM=128 rows x BN=NT*16 cols per block, BK=64, 4 waves (32 rows each).
// A source: bf16 for k<ksplit (global_load_lds, per-lane source carries gather
// + chunk XOR-swizzle; chunks with col>=k1valid redirected to zbuf), fp32 for
// k>=ksplit (reg-staged + converted, masked by k2valid).
// B source: WT [nstrips*BN][kpad] bf16 (zero-padded by builders), gload_lds.
// LDS layout: [row][64] bf16 with 16B-chunk swizzle p = c ^ (row&7) -> 2-way
// bank aliasing only (free) on ds_read_b128 fragment reads.
// MFMA 16x16x32 (m89-verified): A[m=lo][k=quad*8+j], B[k][n=lo], C col=lo,row=quad*4+r.
template<int NT>
__global__ __launch_bounds__(256) void mm_tile(
    const bf16* __restrict__ A1, int lda1, int ksplit, int k1valid,
    const float* __restrict__ A2, int lda2, int k2valid,
    const int* __restrict__ gather,
    const bf16* __restrict__ WT, int kpad,
    const bf16* __restrict__ zbuf,
    const float* __restrict__ bias,
    bf16* __restrict__ C, int ldc,
    int M, int nvalid, int act)
{
  constexpr int BN = NT*16;
  constexpr int BITERS = (NT*128 + 255)/256;
  __shared__ bf16 Alds[128*64];
  __shared__ bf16 Blds[BN*64];

  const int tid  = threadIdx.x;
  const int wave = tid>>6, lane = tid&63;
  const int quad = lane>>4, lo = lane&15;
  const int nstrip = blockIdx.y;
  WT += (size_t)nstrip*BN*kpad;
  C  += (size_t)nstrip*BN;
  if(bias) bias += nstrip*BN;
  const int nval = nvalid - nstrip*BN;
  const int row0 = blockIdx.x*128;

  const int srow = tid>>3;     // 0..31  (8 chunks per 64-elem row)
  const int pl   = tid&7;      // physical chunk (linear LDS dest)

  const char*  a1p[4];
  const float* a2p[4];
  int   ccol[4];
  char* adst[4];
  const char* bp[BITERS];
  char* bdst[BITERS];
  bool  bok[BITERS];

#pragma unroll
  for(int i=0;i<4;i++){
    int rl = i*32 + srow;                 // local A row 0..127
    int rg = row0 + rl; if(rg > M-1) rg = M-1;
    int ar = gather ? gather[rg] : rg;
    int c  = pl ^ (rl & 7);               // logical chunk this thread fetches
    ccol[i] = c*8;
    a1p[i] = (const char*)A1 + (size_t)ar*lda1*2 + c*16;
    a2p[i] = A2 + (size_t)ar*lda2 + c*8;
    adst[i] = (char*)Alds + i*4096 + wave*1024;
  }
#pragma unroll
  for(int i=0;i<BITERS;i++){
    int rl = i*32 + srow;                 // B row (output col within strip)
    int c  = pl ^ (rl & 7);
    bok[i] = (rl < BN);                   // wave-uniform (BN mult of 16, rows per wave 8)
    bp[i]  = (const char*)WT + (size_t)rl*kpad*2 + c*16;
    bdst[i] = (char*)Blds + i*4096 + wave*1024;
  }

  f32x4 acc[2][NT];
#pragma unroll
  for(int m=0;m<2;m++)
#pragma unroll
    for(int n=0;n<NT;n++) acc[m][n] = (f32x4){0.f,0.f,0.f,0.f};

  const int ktiles = kpad >> 6;
  for(int kt=0; kt<ktiles; kt++){
    const int kb = kt<<6;
    // ---- stage A ----
    if(kb < ksplit){
#pragma unroll
      for(int i=0;i<4;i++){
        const char* s = (kb + ccol[i] < k1valid) ? (a1p[i] + kb*2) : (const char*)zbuf;
        gload_lds16(s, adst[i]);
      }
    } else {
      const int kof = kb - ksplit;
#pragma unroll
      for(int i=0;i<4;i++){
        int kk = kof + ccol[i];
        const float* ap = a2p[i] + kof;
        float4 f0 = {0.f,0.f,0.f,0.f}, f1 = {0.f,0.f,0.f,0.f};
        if(kk < k2valid)     f0 = *(const float4*)ap;
        if(kk + 4 < k2valid) f1 = *(const float4*)(ap+4);
        s16x8 v;
        v[0]=f2s(f0.x); v[1]=f2s(f0.y); v[2]=f2s(f0.z); v[3]=f2s(f0.w);
        v[4]=f2s(f1.x); v[5]=f2s(f1.y); v[6]=f2s(f1.z); v[7]=f2s(f1.w);
        *(s16x8*)((char*)Alds + (size_t)(i*256+tid)*16) = v;  // physical = pl (linear)
      }
    }
    // ---- stage B ----
#pragma unroll
    for(int i=0;i<BITERS;i++){
      if(bok[i]) gload_lds16(bp[i] + kb*2, bdst[i]);
    }
    __syncthreads();   // compiler drains vmcnt (gload_lds) + lgkm (ds_write) here

    // ---- compute: 2 MFMA k-steps of 32 over this 64-col tile ----
#pragma unroll
    for(int ks=0; ks<2; ks++){
      s16x8 af[2];
#pragma unroll
      for(int m=0;m<2;m++){
        int rl = wave*32 + m*16 + lo;
        int c  = (ks*4 + quad) ^ (rl & 7);   // physical chunk holding logical ks*4+quad
        af[m] = *(const s16x8*)((const char*)Alds + rl*128 + c*16);
      }
#pragma unroll
      for(int n=0;n<NT;n++){
        int rb = n*16 + lo;
        int c  = (ks*4 + quad) ^ (rb & 7);
        s16x8 bfr = *(const s16x8*)((const char*)Blds + rb*128 + c*16);
        acc[0][n] = __builtin_amdgcn_mfma_f32_16x16x32_bf16(af[0], bfr, acc[0][n], 0,0,0);
        acc[1][n] = __builtin_amdgcn_mfma_f32_16x16x32_bf16(af[1], bfr, acc[1][n], 0,0,0);
      }
    }
    __syncthreads();
  }

  // ---- epilogue ----
#pragma unroll
  for(int n=0;n<NT;n++){
    int col = n*16 + lo;
    if(col >= nval) continue;
    float bv = bias ? bias[col] : 0.f;
#pragma unroll
    for(int m=0;m<2;m++){
      int r0 = row0 + wave*32 + m*16 + quad*4;
#pragma unroll
      for(int r=0;r<4;r++){
        int row = r0 + r;
        if(row >= M) continue;
        float v = acc[m][n][r] + bv;
        if(act==1) v = fmaxf(v, 0.f);
        else if(act==2) v = tanhf(v);
        C[(size_t)row*ldc + col] = f2b(v);
      }
    }
  }
}

// ------ fused attention: one wave per node; online softmax; skip-add + relu ------
// zpad!=0: also zero output cols 100..111 (for 112-padded h2)
__global__ __launch_bounds__(256) void k_attn(
    const int* __restrict__ rowptr, const int* __restrict__ elist,
    const int* __restrict__ srcv,
    const bf16* __restrict__ qkvs, const bf16* __restrict__ eh,
    bf16* __restrict__ hout, int ldh, int colofs, int zpad)
{
  int wave = threadIdx.x>>6, lane = threadIdx.x&63;
  int node = blockIdx.x*4 + wave;
  if(node >= NN) return;
  bool act = (lane < 50);
  float q0=0.f, q1=0.f;
  const unsigned* qrow = (const unsigned*)(qkvs + (size_t)node*400);
  if(act){ unsigned u = qrow[lane]; q0=u2f_lo(u); q1=u2f_hi(u); }
  int s0 = rowptr[node], s1 = rowptr[node+1];
  float m = -3.4e38f, d = 0.f, a0 = 0.f, a1 = 0.f;
  for(int j=s0; j<s1; j++){
    int e = elist[j];
    int sn = srcv[e];
    float p = 0.f, e0=0.f, e1=0.f;
    if(act){
      unsigned uk = ((const unsigned*)(qkvs + (size_t)sn*400 + 100))[lane];
      unsigned ue = ((const unsigned*)(eh   + (size_t)e*100))[lane];
      e0=u2f_lo(ue); e1=u2f_hi(ue);
      p = q0*(u2f_lo(uk)+e0) + q1*(u2f_hi(uk)+e1);
    }
    for(int off=32; off; off>>=1) p += __shfl_xor(p, off);
    float alpha = p * 0.1f;
    float mn = fmaxf(m, alpha);
    float sc = expf(m - mn);
    float wv = expf(alpha - mn);
    d = d*sc + wv;
    if(act){
      unsigned uv = ((const unsigned*)(qkvs + (size_t)sn*400 + 200))[lane];
      a0 = a0*sc + wv*(u2f_lo(uv)+e0);
      a1 = a1*sc + wv*(u2f_hi(uv)+e1);
    }
    m = mn;
  }
  if(act){
    float inv = 1.f/(d + 1e-16f);
    unsigned us = ((const unsigned*)(qkvs + (size_t)node*400 + 300))[lane];
    float h0 = fmaxf(u2f_lo(us) + a0*inv, 0.f);
    float h1 = fmaxf(u2f_hi(us) + a1*inv, 0.f);
    bf16* op = hout + (size_t)node*ldh + colofs + lane*2;
    op[0] = f2b(h0); op[1] = f2b(h1);
  } else if(zpad && lane < 56){
    bf16* op = hout + (size_t)node*ldh + colofs + lane*2;
    op[0] = f2b(0.f); op[1] = f2b(0.f);
  }
}

// ------ linkpred final layer: out[e] = t3[e] @ w4 + b4 (K=50, N=2, fp32) ------
__global__ void k_lpout(const bf16* __restrict__ t3, const float* __restrict__ w4,
                        const float* __restrict__ b4, float* __restrict__ out,
                        int base, int n){
  int i = blockIdx.x*blockDim.x + threadIdx.x;
  if(i >= n*2) return;
  int g = i>>1, j = i&1;
  const bf16* tp = t3 + (size_t)g*50;
  float s = 0.f;
  for(int k=0;k<50;k++) s += b2f(tp[k])*w4[k*2+j];
  out[(size_t)(base+g)*2 + j] = s + b4[j];
}

extern "C" void kernel_launch(void* const* d_in, const int* in_sizes, int n_in,
                              void* d_out, int out_size, void* d_ws, size_t ws_size,
                              hipStream_t stream){
  const float* x       = (const float*)d_in[0];
  const float* msg     = (const float*)d_in[1];
  const float* time_w  = (const float*)d_in[2];
  const float* time_b  = (const float*)d_in[3];
  const float* c1_qw=(const float*)d_in[4];  const float* c1_qb=(const float*)d_in[5];
  const float* c1_kw=(const float*)d_in[6];  const float* c1_kb=(const float*)d_in[7];
  const float* c1_vw=(const float*)d_in[8];  const float* c1_vb=(const float*)d_in[9];
  const float* c1_ew=(const float*)d_in[10];
  const float* c1_sw=(const float*)d_in[11]; const float* c1_sb=(const float*)d_in[12];
  const float* c2_qw=(const float*)d_in[13]; const float* c2_qb=(const float*)d_in[14];
  const float* c2_kw=(const float*)d_in[15]; const float* c2_kb=(const float*)d_in[16];
  const float* c2_vw=(const float*)d_in[17]; const float* c2_vb=(const float*)d_in[18];
  const float* c2_ew=(const float*)d_in[19];
  const float* c2_sw=(const float*)d_in[20]; const float* c2_sb=(const float*)d_in[21];
  const float* lp_src_w=(const float*)d_in[22]; const float* lp_src_b=(const float*)d_in[23];
  const float* lp_dst_w=(const float*)d_in[24]; const float* lp_dst_b=(const float*)d_in[25];
  const float* lp1_w=(const float*)d_in[26]; const float* lp1_b=(const float*)d_in[27];
  const float* lp2_w=(const float*)d_in[28]; const float* lp2_b=(const float*)d_in[29];
  const float* lp3_w=(const float*)d_in[30]; const float* lp3_b=(const float*)d_in[31];
  const float* lp4_w=(const float*)d_in[32]; const float* lp4_b=(const float*)d_in[33];
  const int* last_update=(const int*)d_in[34];
  const int* tt =(const int*)d_in[35];
  const int* edge_index=(const int*)d_in[36];
  const int* src = edge_index;
  const int* dst = edge_index + EE;
  float* out = (float*)d_out;

  // ---- workspace: peak ~199.72 MB (< proved-safe 201.8 MB) ----
  char* ws = (char*)d_ws;
  bf16*  h1    = (bf16*) (ws + 0);             // N*800 bf16 = 80,000,000
  bf16*  relpad= (bf16*) (ws + 80000000);      // E*112 bf16 = 33,600,000
  bf16*  eh    = (bf16*) (ws + 113600000);     // E*100 bf16 = 30,000,000
  bf16*  qkvs  = (bf16*) (ws + 143600000);     // N*400 bf16 = 40,000,000
  bf16*  h2p   = (bf16*) (ws + 183600000);     // N*112 bf16 = 11,200,000
  int*   rowptr= (int*)  (ws + 194800000);     // N+1
  int*   elist = (int*)  (ws + 195000064);     // E
  int*   deg   = (int*)  (ws + 195600064);     // N
  int*   cursor= (int*)  (ws + 195800064);     // N
  bf16* c1all  = (bf16*)(ws + 196000064);  // 8 x [448][128] = 917,504
  bf16* c1eall = (bf16*)(ws + 196917568);  // 8 x [112][256] = 458,752
  bf16* c2all  = (bf16*)(ws + 197376320);  // [448][896]     = 802,816
  bf16* c2e    = (bf16*)(ws + 198179136);  // [112][256]     = 57,344
  bf16* lpswt  = (bf16*)(ws + 198236480);  // [224][128]     = 57,344
  bf16* lpdwt  = (bf16*)(ws + 198293824);  // [224][128]     = 57,344
  bf16* lp1t   = (bf16*)(ws + 198351168);  // [896][512]     = 917,504
  bf16* lp2t   = (bf16*)(ws + 199268672);  // [224][896]     = 401,408
  bf16* lp3t   = (bf16*)(ws + 199670080);  // [64][256]      = 32,768
  float* c1ball= (float*)(ws + 199702848); // [8][400]       = 12,800
  float* c2ball= (float*)(ws + 199715648); // [400]          = 1,600
  bf16* zbuf   = (bf16*)(ws + 199717248);  // 64 B zeros -> ends 199,717,312
  // linkpred-phase overlays (conv buffers 0..183.6MB dead):
  bf16* lhh = (bf16*)(ws + 0);             // EH*400 bf16 = 60 MB
  bf16* lt1 = (bf16*)(ws + 60000000);      // EH*800 bf16 = 120 MB -> 180 MB
  bf16* lt2 = (bf16*)(ws + 0);             // EH*200 bf16 = 30 MB (hh dead)
  bf16* lt3 = (bf16*)(ws + 30000000);      // EH*50  bf16 = 7.5 MB

  // ---- weight conversion ----
  k_wtc1<<<(8*448*128+255)/256,256,0,stream>>>(c1_qw,c1_kw,c1_vw,c1_sw,c1all);
  for(int h=0; h<8; h++)
    k_wte<<<(112*256+255)/256,256,0,stream>>>(c1_ew, 800, h*100, c1eall + (size_t)h*112*256);
  k_wte<<<(112*256+255)/256,256,0,stream>>>(c2_ew, 100, 0, c2e);
  k_wt2<<<(100*896+255)/256,256,0,stream>>>(c2_qw,800,100,0,100,c2all,         896,100);
  k_wt2<<<(100*896+255)/256,256,0,stream>>>(c2_kw,800,100,0,100,c2all+100*896, 896,100);
  k_wt2<<<(100*896+255)/256,256,0,stream>>>(c2_vw,800,100,0,100,c2all+200*896, 896,100);
  k_wt2<<<(100*896+255)/256,256,0,stream>>>(c2_sw,800,100,0,100,c2all+300*896, 896,100);
  k_wt2<<<(48*896+255)/256,256,0,stream>>>(c2_sw,800,100,0,0,   c2all+400*896, 896,48);
  k_wt2<<<(224*128+255)/256,256,0,stream>>>(lp_src_w,100,200,0,200,lpswt,128,224);
  k_wt2<<<(224*128+255)/256,256,0,stream>>>(lp_dst_w,100,200,0,200,lpdwt,128,224);
  k_wt2<<<(896*512+255)/256,256,0,stream>>>(lp1_w,400,800,0,800,lp1t,512,896);
  k_wt2<<<(224*896+255)/256,256,0,stream>>>(lp2_w,800,200,0,200,lp2t,896,224);
  k_wt2<<<(64*256+255)/256,256,0,stream>>>(lp3_w,200,50,0,50,lp3t,256,64);
  k_bstack<<<(3200+255)/256,256,0,stream>>>(c1_qb,c1_kb,c1_vb,c1_sb,100,8,c1ball);
  k_bstack<<<(400+255)/256,256,0,stream>>>(c2_qb,c2_kb,c2_vb,c2_sb,100,1,c2ball);
  k_zero<<<1,64,0,stream>>>((int*)zbuf, 16);

  // ---- CSR build ----
  k_zero   <<<(NN+255)/256, 256, 0, stream>>>(deg, NN);
  k_zero   <<<(NN+255)/256, 256, 0, stream>>>(cursor, NN);
  k_hist   <<<(EE+255)/256, 256, 0, stream>>>(dst, deg);
  k_scan   <<<1, 1024, 0, stream>>>(deg, rowptr);
  k_scatter<<<(EE+255)/256, 256, 0, stream>>>(dst, rowptr, cursor, elist);

  // ---- time encoding ----
  k_relenc<<<(EE*112+255)/256, 256, 0, stream>>>(src, tt, last_update, time_w, time_b, relpad);

  int gN = (NN + 127)/128;   // 391
  int gE = (EE + 127)/128;   // 1172
  int gL = (EH + 127)/128;   // 586
  int gA = (NN + 3)/4;

  // ---- conv1: per head = stacked GEMM (4 n-strips of 112) + edge GEMM + fused attention
  for(int h=0; h<8; h++){
    mm_tile<7><<<dim3(gN,4),256,0,stream>>>(nullptr,0,0,0, x,100,100, nullptr,
        c1all + (size_t)h*448*128, 128, zbuf, c1ball + h*400, qkvs,400, NN,400,0);
    mm_tile<7><<<dim3(gE,1),256,0,stream>>>(relpad,112,128,112, msg,100,100, nullptr,
        c1eall + (size_t)h*112*256, 256, zbuf, nullptr, eh,100, EE,100,0);
    k_attn<<<gA,256,0,stream>>>(rowptr, elist, src, qkvs, eh, h1, 800, h*100, 0);
  }

  // ---- conv2 (h2 written 112-padded, pad cols zeroed) ----
  mm_tile<7><<<dim3(gN,4),256,0,stream>>>(h1,800,896,800, nullptr,0,0, nullptr,
      c2all,896, zbuf, c2ball, qkvs,400, NN,400,0);
  mm_tile<7><<<dim3(gE,1),256,0,stream>>>(relpad,112,128,112, msg,100,100, nullptr,
      c2e,256, zbuf, nullptr, eh,100, EE,100,0);
  k_attn<<<gA,256,0,stream>>>(rowptr, elist, src, qkvs, eh, h2p, 112, 0, 1);

  // ---- link predictor: tiled-MFMA chain, 2 edge-halves ----
  for(int half=0; half<2; half++){
    const int* esrc = src + half*EH;
    const int* edst = dst + half*EH;
    // hh[:,0:200] = h2[src]@Wsrc+b ; hh[:,200:400] = h2[dst]@Wdst+b  (gathered A, K=100)
    mm_tile<7><<<dim3(gL,2),256,0,stream>>>(h2p,112,128,112, nullptr,0,0, esrc,
        lpswt,128, zbuf, lp_src_b, lhh,400, EH,200,0);
    mm_tile<7><<<dim3(gL,2),256,0,stream>>>(h2p,112,128,112, nullptr,0,0, edst,
        lpdwt,128, zbuf, lp_dst_b, lhh+200,400, EH,200,0);
    // t1 = tanh(hh@W1+b1): K=400(512), N=800 via 8 n-strips of 112
    mm_tile<7><<<dim3(gL,8),256,0,stream>>>(lhh,400,512,400, nullptr,0,0, nullptr,
        lp1t,512, zbuf, lp1_b, lt1,800, EH,800,2);
    // t2 = tanh(t1@W2+b2): K=800(896), N=200
    mm_tile<7><<<dim3(gL,2),256,0,stream>>>(lt1,800,896,800, nullptr,0,0, nullptr,
        lp2t,896, zbuf, lp2_b, lt2,200, EH,200,2);
    // t3 = tanh(t2@W3+b3): K=200(256), N=50
    mm_tile<4><<<dim3(gL,1),256,0,stream>>>(lt2,200,256,200, nullptr,0,0, nullptr,
        lp3t,256, zbuf, lp3_b, lt3,50, EH,50,2);
    // out = t3@W4+b4
    k_lpout<<<(EH*2+255)/256,256,0,stream>>>(lt3, lp4_w, lp4_b, out, half*EH, EH);
  }

  (void)in_sizes; (void)n_in; (void)out_size; (void)ws_size;
}

// Round 2
// 2281.050 us; speedup vs baseline: 1.6855x; 1.0641x over previous
//
#include <hip/hip_runtime.h>
#include <hip/hip_bf16.h>
#include <math.h>

typedef __hip_bfloat16 bf16;
typedef short s16x8 __attribute__((ext_vector_type(8)));
typedef float f32x4 __attribute__((ext_vector_type(4)));

#define NN 50000
#define EE 150000
#define EH 75000   // linkpred edge-chunk (2 halves) so t1 fits workspace

static __device__ __forceinline__ float b2f(bf16 x){ return __bfloat162float(x); }
static __device__ __forceinline__ bf16 f2b(float x){ return __float2bfloat16(x); }
static __device__ __forceinline__ short f2s(float x){
  union { bf16 b; short s; } u; u.b = f2b(x); return u.s;
}
static __device__ __forceinline__ float u2f_lo(unsigned u){ union{unsigned i;float f;}c; c.i=u<<16; return c.f; }
static __device__ __forceinline__ float u2f_hi(unsigned u){ union{unsigned i;float f;}c; c.i=u&0xffff0000u; return c.f; }

// fast tanh: 1 - 2/(e^{2|x|}+1), sign-restored. |err| ~1e-5 << bf16 quantum.
// e -> inf for |x|>~44: 2/inf = 0 -> t=1 (no NaN).
static __device__ __forceinline__ float fast_tanh(float x){
  float a = fabsf(x);
  float e = __expf(2.0f*a);
  float t = 1.0f - __fdividef(2.0f, e + 1.0f);
  return x < 0.f ? -t : t;
}

// async global->LDS, 16B per lane. LDS dest is wave-uniform base + lane*16;
// global source address is per-lane (carries gather + swizzle).
static __device__ __forceinline__ void gload_lds16(const void* g, void* l){
  __builtin_amdgcn_global_load_lds((const __attribute__((address_space(1))) void*)g,
                                   (__attribute__((address_space(3))) void*)l, 16, 0, 0);
}

// ---------------- utility ----------------
__global__ void k_zero(int* __restrict__ p, int n){
  int i = blockIdx.x*blockDim.x + threadIdx.x;
  if(i<n) p[i]=0;
}

// ---------------- CSR build ----------------
__global__ void k_hist(const int* __restrict__ dst, int* __restrict__ deg){
  int i = blockIdx.x*blockDim.x + threadIdx.x;
  if(i<EE) atomicAdd(&deg[dst[i]], 1);
}

__global__ void k_scan(const int* __restrict__ deg, int* __restrict__ rowptr){
  __shared__ int part[1024];
  int tid = threadIdx.x;
  const int n = NN;
  int chunk = (n + 1023)/1024;
  int start = tid*chunk;
  int end = start + chunk; if(end > n) end = n;
  int s = 0;
  for(int i=start;i<end;i++) s += deg[i];
  part[tid] = s; __syncthreads();
  for(int off=1; off<1024; off<<=1){
    int v = (tid>=off)? part[tid-off] : 0;
    __syncthreads();
    part[tid] += v;
    __syncthreads();
  }
  int run = (tid==0)? 0 : part[tid-1];
  for(int i=start;i<end;i++){ rowptr[i]=run; run += deg[i]; }
  if(tid==0) rowptr[n] = part[1023];
}

__global__ void k_scatter(const int* __restrict__ dst, const int* __restrict__ rowptr,
                          int* __restrict__ cursor, int* __restrict__ elist){
  int e = blockIdx.x*blockDim.x + threadIdx.x;
  if(e<EE){ int d=dst[e]; int p=atomicAdd(&cursor[d],1); elist[rowptr[d]+p]=e; }
}

// ------- time encoding -> relpad [E,112] (cols 100..111 zero) -------
__global__ void k_relenc(const int* __restrict__ src, const int* __restrict__ tt,
                         const int* __restrict__ lu, const float* __restrict__ tw,
                         const float* __restrict__ tb, bf16* __restrict__ rel){
  int i = blockIdx.x*blockDim.x + threadIdx.x;
  if(i >= EE*112) return;
  int e = i/112, c = i - e*112;
  float v = 0.f;
  if(c < 100){
    float rt  = (float)(lu[src[e]] - tt[e]);
    float arg = __fadd_rn(__fmul_rn(rt, tw[c]), tb[c]);
    v = cosf(arg);
  }
  rel[i] = f2b(v);
}

// ------- fp32 [R][incols] -> bf16 [R][outcols] row-major, zero-padded ----
__global__ void k_cvtpad(const float* __restrict__ in, int incols,
                         bf16* __restrict__ outp, int outcols, int total){
  int i = blockIdx.x*blockDim.x + threadIdx.x;
  if(i >= total) return;
  int r = i/outcols, c = i - r*outcols;
  outp[i] = f2b(c < incols ? in[(size_t)r*incols + c] : 0.f);
}

// ------- generic weight transpose: WT[n][k] = W[k][colofs+n], bf16, zero-pad --------
__global__ void k_wt2(const float* __restrict__ W, int K, int N, int colofs, int ncols,
                      bf16* __restrict__ WT, int kpad, int nrows){
  int i = blockIdx.x*blockDim.x + threadIdx.x;
  if(i >= nrows*kpad) return;
  int n = i / kpad, k = i - n*kpad;
  float v = (n<ncols && k<K)? W[(size_t)k*N + colofs + n] : 0.f;
  WT[i] = f2b(v);
}

// ------- conv1 stacked weights: 8 heads x [448 rows: q|k|v|s|pad][128] ---------------
__global__ void k_wtc1(const float* __restrict__ qw, const float* __restrict__ kw,
                       const float* __restrict__ vw, const float* __restrict__ sw,
                       bf16* __restrict__ outp){
  int i = blockIdx.x*blockDim.x + threadIdx.x;
  if(i >= 8*448*128) return;
  int h = i/(448*128), r = (i/128)%448, k = i&127;
  float v = 0.f;
  if(r < 400 && k < 100){
    int s = r/100, n = r - s*100;
    const float* W = s==0? qw : s==1? kw : s==2? vw : sw;
    v = W[(size_t)k*800 + h*100 + n];
  }
  outp[i] = f2b(v);
}

// ------- edge weights [112][256]: k<100 -> rel rows, 128..227 -> msg rows (shifted) ---
__global__ void k_wte(const float* __restrict__ ew, int N, int colofs,
                      bf16* __restrict__ outp){
  int i = blockIdx.x*blockDim.x + threadIdx.x;
  if(i >= 112*256) return;
  int r = i>>8, k = i&255;
  float v = 0.f;
  if(r < 100){
    if(k < 100) v = ew[(size_t)k*N + colofs + r];
    else if(k >= 128 && k < 228) v = ew[(size_t)(k-28)*N + colofs + r];
  }
  outp[i] = f2b(v);
}

// ------- stacked bias ----------------
__global__ void k_bstack(const float* __restrict__ b0, const float* __restrict__ b1,
                         const float* __restrict__ b2, const float* __restrict__ b3,
                         int W, int H, float* __restrict__ outp){
  int i = blockIdx.x*blockDim.x + threadIdx.x;
  if(i >= H*4*W) return;
  int h = i/(4*W), r = i - h*4*W, s = r/W, c = r - s*W;
  const float* b = s==0? b0 : s==1? b1 : s==2? b2 : b3;
  outp[i] = b[h*W + c];
}

// ---------------- LDS-staged tiled MFMA GEMM, BK=32, double-buffered ----------------
// BM=128 x BN=NT*16 per block, 4 waves (32 rows each), ONE __syncthreads per K-tile:
//   stage(next tile) -> compute(cur) -> [cvt+ds_write fp32 next] -> barrier
// so HBM latency of the prefetch hides under the MFMAs.
// LDS slot s = row*4 + cp (16B chunks); logical chunk q = cp ^ ((row>>1)&3):
// fragment ds_read_b128 hits 8 distinct 16B cols per 16 lanes -> free 2-way.
// A: k<ksplit from bf16 A1 (gload_lds, chunks >= k1valid redirected to zbuf);
//    k>=ksplit from fp32 A2f (issue loads early, cvt+ds_write after compute).
// MFMA 16x16x32 (m89-verified): A[m=lo][k=quad*8+j], B[k][n=lo], C col=lo,row=quad*4+r.
// Epilogue: bias+act, then lane-pair shfl packs col pairs -> coalesced b32 stores.
template<int NT>
__global__ __launch_bounds__(256) void mm_tile(
    const bf16* __restrict__ A1, int lda1, int ksplit, int k1valid,
    const float* __restrict__ A2f, int lda2, int k2valid,
    const int* __restrict__ gather,
    const bf16* __restrict__ WT, int kpad,
    const bf16* __restrict__ zbuf,
    const float* __restrict__ bias,
    bf16* __restrict__ C, int ldc,
    int M, int nvalid, int act)
{
  constexpr int BN = NT*16;
  constexpr int BP = (BN*4 + 255)/256;    // B staging passes
  constexpr int ABYTES = 128*32*2;        // 8192
  constexpr int BBYTES = BN*32*2;
  constexpr int BUFSZ  = ABYTES + BBYTES;
  __shared__ __align__(16) char lds[2*BUFSZ];

  const int tid  = threadIdx.x;
  const int wave = tid>>6, lane = tid&63;
  const int quad = lane>>4, lo = lane&15;
  const int nstrip = blockIdx.y;
  WT += (size_t)nstrip*BN*kpad;
  C  += (size_t)nstrip*BN;
  if(bias) bias += nstrip*BN;
  const int nval = nvalid - nstrip*BN;
  const int row0 = blockIdx.x*128;

  // ---- staging address precompute ----
  const char*  a1base[2];
  const float* a2base[2];
  int acol0[2];
#pragma unroll
  for(int p=0;p<2;p++){
    int s = p*256 + tid;
    int row = s>>2, cp = s&3;
    int q = cp ^ ((row>>1)&3);
    int col0 = q*8;
    int rg = row0 + row; if(rg > M-1) rg = M-1;
    int ar = gather ? gather[rg] : rg;
    acol0[p]  = col0;
    a1base[p] = (const char*)A1 + ((size_t)ar*lda1 + col0)*2;
    a2base[p] = A2f ? (A2f + (size_t)ar*lda2 + col0 - ksplit) : nullptr;
  }
  const char* bbase[BP];
  bool bval[BP];
#pragma unroll
  for(int q=0;q<BP;q++){
    int s = q*256 + tid;
    int rb = s>>2, cp = s&3;
    int rbc = rb < BN ? rb : BN-1;
    int lq = cp ^ ((rbc>>1)&3);
    bval[q]  = (s < BN*4);
    bbase[q] = (const char*)WT + ((size_t)rbc*kpad + lq*8)*2;
  }

  f32x4 acc[2][NT];
#pragma unroll
  for(int m=0;m<2;m++)
#pragma unroll
    for(int n=0;n<NT;n++) acc[m][n] = (f32x4){0.f,0.f,0.f,0.f};

  float4 pf0[2], pf1[2];

  auto stageA1 = [&](char* buf, int kb){
#pragma unroll
    for(int p=0;p<2;p++){
      const char* s = (kb + acol0[p] < k1valid) ? (a1base[p] + (size_t)kb*2)
                                                : (const char*)zbuf;
      gload_lds16(s, buf + p*4096 + wave*1024);
    }
  };
  auto loadA2 = [&](int kb){
#pragma unroll
    for(int p=0;p<2;p++){
      int kk = kb - ksplit + acol0[p];
      const float* ap = a2base[p] + kb;
      pf0[p] = (kk   < k2valid) ? *(const float4*)ap     : (float4){0.f,0.f,0.f,0.f};
      pf1[p] = (kk+4 < k2valid) ? *(const float4*)(ap+4) : (float4){0.f,0.f,0.f,0.f};
    }
  };
  auto writeA2 = [&](char* buf){
#pragma unroll
    for(int p=0;p<2;p++){
      s16x8 v;
      v[0]=f2s(pf0[p].x); v[1]=f2s(pf0[p].y); v[2]=f2s(pf0[p].z); v[3]=f2s(pf0[p].w);
      v[4]=f2s(pf1[p].x); v[5]=f2s(pf1[p].y); v[6]=f2s(pf1[p].z); v[7]=f2s(pf1[p].w);
      *(s16x8*)(buf + p*4096 + (size_t)tid*16) = v;
    }
  };
  auto stageB = [&](char* buf, int kb){
#pragma unroll
    for(int q=0;q<BP;q++){
      if(bval[q]) gload_lds16(bbase[q] + (size_t)kb*2, buf + ABYTES + q*4096 + wave*1024);
    }
  };
  auto compute = [&](const char* buf){
    s16x8 af[2];
#pragma unroll
    for(int m=0;m<2;m++){
      int rl = wave*32 + m*16 + lo;
      int cp = quad ^ ((rl>>1)&3);
      af[m] = *(const s16x8*)(buf + rl*64 + cp*16);
    }
#pragma unroll
    for(int n=0;n<NT;n++){
      int rb = n*16 + lo;
      int cp = quad ^ ((rb>>1)&3);
      s16x8 bfr = *(const s16x8*)(buf + ABYTES + rb*64 + cp*16);
      acc[0][n] = __builtin_amdgcn_mfma_f32_16x16x32_bf16(af[0], bfr, acc[0][n], 0,0,0);
      acc[1][n] = __builtin_amdgcn_mfma_f32_16x16x32_bf16(af[1], bfr, acc[1][n], 0,0,0);
    }
  };

  // ---- prologue: tile 0 into buf0 ----
  {
    char* b0 = lds;
    if(0 < ksplit || !A2f) stageA1(b0, 0);
    else { loadA2(0); writeA2(b0); }
    stageB(b0, 0);
    __syncthreads();
  }
  // ---- main loop: one barrier per tile, prefetch overlapped with compute ----
  const int ktiles = kpad >> 5;
  for(int kt=0; kt<ktiles; kt++){
    char* cur = lds + (kt&1)*BUFSZ;
    char* nxt = lds + ((kt&1)^1)*BUFSZ;
    int nb = (kt+1)<<5;
    bool havenext = nb < kpad;
    bool fpnx = havenext && nb >= ksplit && A2f;
    if(havenext){
      if(nb < ksplit || !A2f) stageA1(nxt, nb);
      else                    loadA2(nb);       // issue only; cvt+write after compute
      stageB(nxt, nb);
    }
    compute(cur);
    if(fpnx) writeA2(nxt);
    __syncthreads();
  }

  // ---- epilogue: bias + act, lane-pair pack, b32 stores ----
  const int r0 = (lane&1)<<1;
#pragma unroll
  for(int n=0;n<NT;n++){
    int col  = n*16 + lo;
    int pcol = col & ~1;
    bool cok = (pcol < nval);                  // nval always even
    float bv = 0.f;
    if(bias && col < nval) bv = bias[col];
#pragma unroll
    for(int m=0;m<2;m++){
      float v[4];
#pragma unroll
      for(int r=0;r<4;r++){
        float t = acc[m][n][r] + bv;
        if(act==1) t = fmaxf(t, 0.f);
        else if(act==2) t = fast_tanh(t);
        v[r] = t;
      }
      unsigned mylo = (unsigned)(unsigned short)f2s(v[r0])
                    | ((unsigned)(unsigned short)f2s(v[r0+1])<<16);
      unsigned snd  = (unsigned)(unsigned short)f2s(v[r0^2])
                    | ((unsigned)(unsigned short)f2s(v[(r0^2)+1])<<16);
      unsigned got  = (unsigned)__shfl_xor((int)snd, 1);
      unsigned w0, w1;
      if(lane&1){ w0 = (got & 0xffffu) | (mylo<<16); w1 = (got>>16) | (mylo & 0xffff0000u); }
      else      { w0 = (mylo & 0xffffu) | (got<<16); w1 = (mylo>>16) | (got & 0xffff0000u); }
      if(cok){
        int prow = row0 + wave*32 + m*16 + quad*4 + r0;
        if(prow   < M) *(unsigned*)(C + (size_t)prow*ldc + pcol) = w0;
        if(prow+1 < M) *(unsigned*)(C + (size_t)(prow+1)*ldc + pcol) = w1;
      }
    }
  }
}

// ------ fused attention: one wave per node; online softmax; skip-add + relu ------
// zpad!=0: also zero output cols 100..111 (for 112-padded h2)
__global__ __launch_bounds__(256) void k_attn(
    const int* __restrict__ rowptr, const int* __restrict__ elist,
    const int* __restrict__ srcv,
    const bf16* __restrict__ qkvs, const bf16* __restrict__ eh,
    bf16* __restrict__ hout, int ldh, int colofs, int zpad)
{
  int wave = threadIdx.x>>6, lane = threadIdx.x&63;
  int node = blockIdx.x*4 + wave;
  if(node >= NN) return;
  bool act = (lane < 50);
  float q0=0.f, q1=0.f;
  const unsigned* qrow = (const unsigned*)(qkvs + (size_t)node*400);
  if(act){ unsigned u = qrow[lane]; q0=u2f_lo(u); q1=u2f_hi(u); }
  int s0 = rowptr[node], s1 = rowptr[node+1];
  float m = -3.4e38f, d = 0.f, a0 = 0.f, a1 = 0.f;
  for(int j=s0; j<s1; j++){
    int e = elist[j];
    int sn = srcv[e];
    float p = 0.f, e0=0.f, e1=0.f;
    if(act){
      unsigned uk = ((const unsigned*)(qkvs + (size_t)sn*400 + 100))[lane];
      unsigned ue = ((const unsigned*)(eh   + (size_t)e*100))[lane];
      e0=u2f_lo(ue); e1=u2f_hi(ue);
      p = q0*(u2f_lo(uk)+e0) + q1*(u2f_hi(uk)+e1);
    }
    for(int off=32; off; off>>=1) p += __shfl_xor(p, off);
    float alpha = p * 0.1f;
    float mn = fmaxf(m, alpha);
    float sc = __expf(m - mn);
    float wv = __expf(alpha - mn);
    d = d*sc + wv;
    if(act){
      unsigned uv = ((const unsigned*)(qkvs + (size_t)sn*400 + 200))[lane];
      a0 = a0*sc + wv*(u2f_lo(uv)+e0);
      a1 = a1*sc + wv*(u2f_hi(uv)+e1);
    }
    m = mn;
  }
  if(act){
    float inv = 1.f/(d + 1e-16f);
    unsigned us = ((const unsigned*)(qkvs + (size_t)node*400 + 300))[lane];
    float h0 = fmaxf(u2f_lo(us) + a0*inv, 0.f);
    float h1 = fmaxf(u2f_hi(us) + a1*inv, 0.f);
    bf16* op = hout + (size_t)node*ldh + colofs + lane*2;
    op[0] = f2b(h0); op[1] = f2b(h1);
  } else if(zpad && lane < 56){
    bf16* op = hout + (size_t)node*ldh + colofs + lane*2;
    op[0] = f2b(0.f); op[1] = f2b(0.f);
  }
}

// ------ linkpred final layer: out[e] = t3[e] @ w4 + b4 (K=50, N=2, fp32) ------
__global__ void k_lpout(const bf16* __restrict__ t3, const float* __restrict__ w4,
                        const float* __restrict__ b4, float* __restrict__ out,
                        int base, int n){
  int i = blockIdx.x*blockDim.x + threadIdx.x;
  if(i >= n*2) return;
  int g = i>>1, j = i&1;
  const bf16* tp = t3 + (size_t)g*50;
  float s = 0.f;
  for(int k=0;k<50;k++) s += b2f(tp[k])*w4[k*2+j];
  out[(size_t)(base+g)*2 + j] = s + b4[j];
}

extern "C" void kernel_launch(void* const* d_in, const int* in_sizes, int n_in,
                              void* d_out, int out_size, void* d_ws, size_t ws_size,
                              hipStream_t stream){
  const float* x       = (const float*)d_in[0];
  const float* msg     = (const float*)d_in[1];
  const float* time_w  = (const float*)d_in[2];
  const float* time_b  = (const float*)d_in[3];
  const float* c1_qw=(const float*)d_in[4];  const float* c1_qb=(const float*)d_in[5];
  const float* c1_kw=(const float*)d_in[6];  const float* c1_kb=(const float*)d_in[7];
  const float* c1_vw=(const float*)d_in[8];  const float* c1_vb=(const float*)d_in[9];
  const float* c1_ew=(const float*)d_in[10];
  const float* c1_sw=(const float*)d_in[11]; const float* c1_sb=(const float*)d_in[12];
  const float* c2_qw=(const float*)d_in[13]; const float* c2_qb=(const float*)d_in[14];
  const float* c2_kw=(const float*)d_in[15]; const float* c2_kb=(const float*)d_in[16];
  const float* c2_vw=(const float*)d_in[17]; const float* c2_vb=(const float*)d_in[18];
  const float* c2_ew=(const float*)d_in[19];
  const float* c2_sw=(const float*)d_in[20]; const float* c2_sb=(const float*)d_in[21];
  const float* lp_src_w=(const float*)d_in[22]; const float* lp_src_b=(const float*)d_in[23];
  const float* lp_dst_w=(const float*)d_in[24]; const float* lp_dst_b=(const float*)d_in[25];
  const float* lp1_w=(const float*)d_in[26]; const float* lp1_b=(const float*)d_in[27];
  const float* lp2_w=(const float*)d_in[28]; const float* lp2_b=(const float*)d_in[29];
  const float* lp3_w=(const float*)d_in[30]; const float* lp3_b=(const float*)d_in[31];
  const float* lp4_w=(const float*)d_in[32]; const float* lp4_b=(const float*)d_in[33];
  const int* last_update=(const int*)d_in[34];
  const int* tt =(const int*)d_in[35];
  const int* edge_index=(const int*)d_in[36];
  const int* src = edge_index;
  const int* dst = edge_index + EE;
  float* out = (float*)d_out;

  // ---- workspace: peak ~199.72 MB (< proved-safe 201.8 MB) ----
  char* ws = (char*)d_ws;
  bf16*  h1    = (bf16*) (ws + 0);             // N*800 bf16 = 80,000,000
  bf16*  relpad= (bf16*) (ws + 80000000);      // E*112 bf16 = 33,600,000
  bf16*  eh    = (bf16*) (ws + 113600000);     // E*100 bf16 = 30,000,000
  bf16*  qkvs  = (bf16*) (ws + 143600000);     // N*400 bf16 = 40,000,000
  bf16*  h2p   = (bf16*) (ws + 183600000);     // N*112 bf16 = 11,200,000
  bf16*  xb    = (bf16*) (ws + 183600000);     // overlay: xb dead before h2p written
  int*   rowptr= (int*)  (ws + 194800000);     // N+1
  int*   elist = (int*)  (ws + 195000064);     // E
  int*   deg   = (int*)  (ws + 195600064);     // N
  int*   cursor= (int*)  (ws + 195800064);     // N
  bf16* c1all  = (bf16*)(ws + 196000064);  // 8 x [448][128] = 917,504
  bf16* c1eall = (bf16*)(ws + 196917568);  // 8 x [112][256] = 458,752
  bf16* c2all  = (bf16*)(ws + 197376320);  // [448][896]     = 802,816
  bf16* c2e    = (bf16*)(ws + 198179136);  // [112][256]     = 57,344
  bf16* lpswt  = (bf16*)(ws + 198236480);  // [224][128]     = 57,344
  bf16* lpdwt  = (bf16*)(ws + 198293824);  // [224][128]     = 57,344
  bf16* lp1t   = (bf16*)(ws + 198351168);  // [896][512]     = 917,504
  bf16* lp2t   = (bf16*)(ws + 199268672);  // [224][896]     = 401,408
  bf16* lp3t   = (bf16*)(ws + 199670080);  // [64][256]      = 32,768
  float* c1ball= (float*)(ws + 199702848); // [8][400]       = 12,800
  float* c2ball= (float*)(ws + 199715648); // [400]          = 1,600
  bf16* zbuf   = (bf16*)(ws + 199717248);  // 64 B zeros -> ends 199,717,312
  // linkpred-phase overlays (conv buffers 0..183.6MB dead):
  bf16* lhh = (bf16*)(ws + 0);             // EH*400 bf16 = 60 MB
  bf16* lt1 = (bf16*)(ws + 60000000);      // EH*800 bf16 = 120 MB -> 180 MB
  bf16* lt2 = (bf16*)(ws + 0);             // EH*200 bf16 = 30 MB (hh dead)
  bf16* lt3 = (bf16*)(ws + 30000000);      // EH*50  bf16 = 7.5 MB

  // ---- weight conversion ----
  k_wtc1<<<(8*448*128+255)/256,256,0,stream>>>(c1_qw,c1_kw,c1_vw,c1_sw,c1all);
  for(int h=0; h<8; h++)
    k_wte<<<(112*256+255)/256,256,0,stream>>>(c1_ew, 800, h*100, c1eall + (size_t)h*112*256);
  k_wte<<<(112*256+255)/256,256,0,stream>>>(c2_ew, 100, 0, c2e);
  k_wt2<<<(100*896+255)/256,256,0,stream>>>(c2_qw,800,100,0,100,c2all,         896,100);
  k_wt2<<<(100*896+255)/256,256,0,stream>>>(c2_kw,800,100,0,100,c2all+100*896, 896,100);
  k_wt2<<<(100*896+255)/256,256,0,stream>>>(c2_vw,800,100,0,100,c2all+200*896, 896,100);
  k_wt2<<<(100*896+255)/256,256,0,stream>>>(c2_sw,800,100,0,100,c2all+300*896, 896,100);
  k_wt2<<<(48*896+255)/256,256,0,stream>>>(c2_sw,800,100,0,0,   c2all+400*896, 896,48);
  k_wt2<<<(224*128+255)/256,256,0,stream>>>(lp_src_w,100,200,0,200,lpswt,128,224);
  k_wt2<<<(224*128+255)/256,256,0,stream>>>(lp_dst_w,100,200,0,200,lpdwt,128,224);
  k_wt2<<<(896*512+255)/256,256,0,stream>>>(lp1_w,400,800,0,800,lp1t,512,896);
  k_wt2<<<(224*896+255)/256,256,0,stream>>>(lp2_w,800,200,0,200,lp2t,896,224);
  k_wt2<<<(64*256+255)/256,256,0,stream>>>(lp3_w,200,50,0,50,lp3t,256,64);
  k_bstack<<<(3200+255)/256,256,0,stream>>>(c1_qb,c1_kb,c1_vb,c1_sb,100,8,c1ball);
  k_bstack<<<(400+255)/256,256,0,stream>>>(c2_qb,c2_kb,c2_vb,c2_sb,100,1,c2ball);
  k_zero<<<1,64,0,stream>>>((int*)zbuf, 16);
  k_cvtpad<<<(NN*112+255)/256,256,0,stream>>>(x, 100, xb, 112, NN*112);

  // ---- CSR build ----
  k_zero   <<<(NN+255)/256, 256, 0, stream>>>(deg, NN);
  k_zero   <<<(NN+255)/256, 256, 0, stream>>>(cursor, NN);
  k_hist   <<<(EE+255)/256, 256, 0, stream>>>(dst, deg);
  k_scan   <<<1, 1024, 0, stream>>>(deg, rowptr);
  k_scatter<<<(EE+255)/256, 256, 0, stream>>>(dst, rowptr, cursor, elist);

  // ---- time encoding ----
  k_relenc<<<(EE*112+255)/256, 256, 0, stream>>>(src, tt, last_update, time_w, time_b, relpad);

  int gN = (NN + 127)/128;   // 391
  int gE = (EE + 127)/128;   // 1172
  int gL = (EH + 127)/128;   // 586
  int gA = (NN + 3)/4;

  // ---- conv1: per head = node GEMM (2 strips of 208) + edge GEMM + fused attention
  for(int h=0; h<8; h++){
    mm_tile<13><<<dim3(gN,2),256,0,stream>>>(xb,112,128,112, nullptr,0,0, nullptr,
        c1all + (size_t)h*448*128, 128, zbuf, c1ball + h*400, qkvs,400, NN,400,0);
    mm_tile<7><<<dim3(gE,1),256,0,stream>>>(relpad,112,128,112, msg,100,100, nullptr,
        c1eall + (size_t)h*112*256, 256, zbuf, nullptr, eh,100, EE,100,0);
    k_attn<<<gA,256,0,stream>>>(rowptr, elist, src, qkvs, eh, h1, 800, h*100, 0);
  }

  // ---- conv2 (h2 written 112-padded, pad cols zeroed) ----
  mm_tile<13><<<dim3(gN,2),256,0,stream>>>(h1,800,896,800, nullptr,0,0, nullptr,
      c2all,896, zbuf, c2ball, qkvs,400, NN,400,0);
  mm_tile<7><<<dim3(gE,1),256,0,stream>>>(relpad,112,128,112, msg,100,100, nullptr,
      c2e,256, zbuf, nullptr, eh,100, EE,100,0);
  k_attn<<<gA,256,0,stream>>>(rowptr, elist, src, qkvs, eh, h2p, 112, 0, 1);

  // ---- link predictor: tiled-MFMA chain, 2 edge-halves ----
  for(int half=0; half<2; half++){
    const int* esrc = src + half*EH;
    const int* edst = dst + half*EH;
    // hh[:,0:200] = h2[src]@Wsrc+b ; hh[:,200:400] = h2[dst]@Wdst+b  (gathered A, K=100)
    mm_tile<13><<<dim3(gL,1),256,0,stream>>>(h2p,112,128,112, nullptr,0,0, esrc,
        lpswt,128, zbuf, lp_src_b, lhh,400, EH,200,0);
    mm_tile<13><<<dim3(gL,1),256,0,stream>>>(h2p,112,128,112, nullptr,0,0, edst,
        lpdwt,128, zbuf, lp_dst_b, lhh+200,400, EH,200,0);
    // t1 = tanh(hh@W1+b1): K=400(512), N=800 via 5 full strips of 160
    mm_tile<10><<<dim3(gL,5),256,0,stream>>>(lhh,400,512,400, nullptr,0,0, nullptr,
        lp1t,512, zbuf, lp1_b, lt1,800, EH,800,2);
    // t2 = tanh(t1@W2+b2): K=800(896), N=200 (1 strip)
    mm_tile<13><<<dim3(gL,1),256,0,stream>>>(lt1,800,896,800, nullptr,0,0, nullptr,
        lp2t,896, zbuf, lp2_b, lt2,200, EH,200,2);
    // t3 = tanh(t2@W3+b3): K=200(256), N=50
    mm_tile<4><<<dim3(gL,1),256,0,stream>>>(lt2,200,256,200, nullptr,0,0, nullptr,
        lp3t,256, zbuf, lp3_b, lt3,50, EH,50,2);
    // out = t3@W4+b4
    k_lpout<<<(EH*2+255)/256,256,0,stream>>>(lt3, lp4_w, lp4_b, out, half*EH, EH);
  }

  (void)in_sizes; (void)n_in; (void)out_size; (void)ws_size;
}

// Round 3
// 2024.838 us; speedup vs baseline: 1.8988x; 1.1265x over previous
//
#include <hip/hip_runtime.h>
#include <hip/hip_bf16.h>
#include <math.h>

typedef __hip_bfloat16 bf16;
typedef short s16x8 __attribute__((ext_vector_type(8)));
typedef float f32x4 __attribute__((ext_vector_type(4)));

#define NN 50000
#define EE 150000
#define EH 75000   // linkpred edge-chunk (2 halves)

static __device__ __forceinline__ float b2f(bf16 x){ return __bfloat162float(x); }
static __device__ __forceinline__ bf16 f2b(float x){ return __float2bfloat16(x); }
static __device__ __forceinline__ short f2s(float x){
  union { bf16 b; short s; } u; u.b = f2b(x); return u.s;
}
static __device__ __forceinline__ float u2f_lo(unsigned u){ union{unsigned i;float f;}c; c.i=u<<16; return c.f; }
static __device__ __forceinline__ float u2f_hi(unsigned u){ union{unsigned i;float f;}c; c.i=u&0xffff0000u; return c.f; }

// fast tanh: 1 - 2/(e^{2|x|}+1), sign-restored. |err| ~1e-5 << bf16 quantum.
static __device__ __forceinline__ float fast_tanh(float x){
  float a = fabsf(x);
  float e = __expf(2.0f*a);
  float t = 1.0f - __fdividef(2.0f, e + 1.0f);
  return x < 0.f ? -t : t;
}

// async global->LDS, 16B per lane (dest = wave-uniform base + lane*16)
static __device__ __forceinline__ void gload_lds16(const void* g, void* l){
  __builtin_amdgcn_global_load_lds((const __attribute__((address_space(1))) void*)g,
                                   (__attribute__((address_space(3))) void*)l, 16, 0, 0);
}

template<int N> static __device__ __forceinline__ void wait_vmcnt(){
  if constexpr(N==0) asm volatile("s_waitcnt vmcnt(0)" ::: "memory");
  else if constexpr(N==1) asm volatile("s_waitcnt vmcnt(1)" ::: "memory");
  else if constexpr(N==2) asm volatile("s_waitcnt vmcnt(2)" ::: "memory");
  else if constexpr(N==3) asm volatile("s_waitcnt vmcnt(3)" ::: "memory");
  else if constexpr(N==4) asm volatile("s_waitcnt vmcnt(4)" ::: "memory");
  else if constexpr(N==5) asm volatile("s_waitcnt vmcnt(5)" ::: "memory");
  else asm volatile("s_waitcnt vmcnt(6)" ::: "memory");
}
static __device__ __forceinline__ void wait_lgkm0(){
  asm volatile("s_waitcnt lgkmcnt(0)" ::: "memory");
}
static __device__ __forceinline__ void memfence(){
  asm volatile("" ::: "memory");
}

// ---------------- utility ----------------
__global__ void k_zero(int* __restrict__ p, int n){
  int i = blockIdx.x*blockDim.x + threadIdx.x;
  if(i<n) p[i]=0;
}

// ---------------- CSR build ----------------
__global__ void k_hist(const int* __restrict__ dst, int* __restrict__ deg){
  int i = blockIdx.x*blockDim.x + threadIdx.x;
  if(i<EE) atomicAdd(&deg[dst[i]], 1);
}

__global__ void k_scan(const int* __restrict__ deg, int* __restrict__ rowptr){
  __shared__ int part[1024];
  int tid = threadIdx.x;
  const int n = NN;
  int chunk = (n + 1023)/1024;
  int start = tid*chunk;
  int end = start + chunk; if(end > n) end = n;
  int s = 0;
  for(int i=start;i<end;i++) s += deg[i];
  part[tid] = s; __syncthreads();
  for(int off=1; off<1024; off<<=1){
    int v = (tid>=off)? part[tid-off] : 0;
    __syncthreads();
    part[tid] += v;
    __syncthreads();
  }
  int run = (tid==0)? 0 : part[tid-1];
  for(int i=start;i<end;i++){ rowptr[i]=run; run += deg[i]; }
  if(tid==0) rowptr[n] = part[1023];
}

__global__ void k_scatter(const int* __restrict__ dst, const int* __restrict__ rowptr,
                          int* __restrict__ cursor, int* __restrict__ elist){
  int e = blockIdx.x*blockDim.x + threadIdx.x;
  if(e<EE){ int d=dst[e]; int p=atomicAdd(&cursor[d],1); elist[rowptr[d]+p]=e; }
}

// ------- time encoding -> relpad [E,112] (cols 100..111 zero) -------
__global__ void k_relenc(const int* __restrict__ src, const int* __restrict__ tt,
                         const int* __restrict__ lu, const float* __restrict__ tw,
                         const float* __restrict__ tb, bf16* __restrict__ rel){
  int i = blockIdx.x*blockDim.x + threadIdx.x;
  if(i >= EE*112) return;
  int e = i/112, c = i - e*112;
  float v = 0.f;
  if(c < 100){
    float rt  = (float)(lu[src[e]] - tt[e]);
    float arg = __fadd_rn(__fmul_rn(rt, tw[c]), tb[c]);
    v = cosf(arg);
  }
  rel[i] = f2b(v);
}

// ------- fp32 [R][incols] -> bf16 [R][outcols] row-major, zero-padded ----
__global__ void k_cvtpad(const float* __restrict__ in, int incols,
                         bf16* __restrict__ outp, int outcols, int total){
  int i = blockIdx.x*blockDim.x + threadIdx.x;
  if(i >= total) return;
  int r = i/outcols, c = i - r*outcols;
  outp[i] = f2b(c < incols ? in[(size_t)r*incols + c] : 0.f);
}

// ------- generic weight transpose: WT[n][k] = W[k][colofs+n], bf16, zero-pad --------
__global__ void k_wt2(const float* __restrict__ W, int K, int N, int colofs, int ncols,
                      bf16* __restrict__ WT, int kpad, int nrows){
  int i = blockIdx.x*blockDim.x + threadIdx.x;
  if(i >= nrows*kpad) return;
  int n = i / kpad, k = i - n*kpad;
  float v = (n<ncols && k<K)? W[(size_t)k*N + colofs + n] : 0.f;
  WT[i] = f2b(v);
}

// ------- conv1 stacked weights: 8 heads x [448 rows: q|k|v|s|pad][128] ---------------
__global__ void k_wtc1(const float* __restrict__ qw, const float* __restrict__ kw,
                       const float* __restrict__ vw, const float* __restrict__ sw,
                       bf16* __restrict__ outp){
  int i = blockIdx.x*blockDim.x + threadIdx.x;
  if(i >= 8*448*128) return;
  int h = i/(448*128), r = (i/128)%448, k = i&127;
  float v = 0.f;
  if(r < 400 && k < 100){
    int s = r/100, n = r - s*100;
    const float* W = s==0? qw : s==1? kw : s==2? vw : sw;
    v = W[(size_t)k*800 + h*100 + n];
  }
  outp[i] = f2b(v);
}

// ------- edge weights [112][256]: k<100 -> rel rows, 128..227 -> msg rows ---
__global__ void k_wte(const float* __restrict__ ew, int N, int colofs,
                      bf16* __restrict__ outp){
  int i = blockIdx.x*blockDim.x + threadIdx.x;
  if(i >= 112*256) return;
  int r = i>>8, k = i&255;
  float v = 0.f;
  if(r < 100){
    if(k < 100) v = ew[(size_t)k*N + colofs + r];
    else if(k >= 128 && k < 228) v = ew[(size_t)(k-28)*N + colofs + r];
  }
  outp[i] = f2b(v);
}

// ------- stacked bias ----------------
__global__ void k_bstack(const float* __restrict__ b0, const float* __restrict__ b1,
                         const float* __restrict__ b2, const float* __restrict__ b3,
                         int W, int H, float* __restrict__ outp){
  int i = blockIdx.x*blockDim.x + threadIdx.x;
  if(i >= H*4*W) return;
  int h = i/(4*W), r = i - h*4*W, s = r/W, c = r - s*W;
  const float* b = s==0? b0 : s==1? b1 : s==2? b2 : b3;
  outp[i] = b[h*W + c];
}

// ------- linkpred fold: WT1f[n][k] bf16, kpad=224 ------------------------------
// k<100:   U[k][n]  = sum_j Ws[k][j]  * W1[j][n]
// 112..211: V[k'][n] = sum_j Wd[k'][j] * W1[200+j][n]   (k'=k-112)
__global__ void k_foldw(const float* __restrict__ sw, const float* __restrict__ dw,
                        const float* __restrict__ w1, bf16* __restrict__ o){
  int i = blockIdx.x*blockDim.x + threadIdx.x;
  if(i >= 800*224) return;
  int n = i/224, k = i - n*224;
  float s = 0.f;
  if(k < 100){
    for(int j=0;j<200;j++) s += sw[k*200+j]*w1[(size_t)j*800+n];
  } else if(k >= 112 && k < 212){
    int kk = k-112;
    for(int j=0;j<200;j++) s += dw[kk*200+j]*w1[(size_t)(200+j)*800+n];
  }
  o[i] = f2b(s);
}
// c[n] = b1[n] + sum_j bs[j]*W1[j][n] + bd[j]*W1[200+j][n]
__global__ void k_foldb(const float* __restrict__ sb, const float* __restrict__ db,
                        const float* __restrict__ w1, const float* __restrict__ b1,
                        float* __restrict__ o){
  int n = blockIdx.x*blockDim.x + threadIdx.x;
  if(n >= 800) return;
  float s = b1[n];
  for(int j=0;j<200;j++) s += sb[j]*w1[(size_t)j*800+n] + db[j]*w1[(size_t)(200+j)*800+n];
  o[n] = s;
}

// ---------------- counted-vmcnt ring-pipelined MFMA GEMM (BK=32, 3 buffers) -----
// BM=128 x BN=NT*16, 4 waves. Per K-tile: wait vmcnt(next-tile count) -> s_barrier
// -> stage tile t+2 (ring buf, depth-2 prefetch) -> compute tile t. Loads never
// drained to 0 in steady state (T4). LDS chunk swizzle p = q ^ ((row>>1)&3) ->
// free 2-way bank aliasing on ds_read_b128.
// A source regions: k<KS from bf16 A1 (gather g1); k>=KS from bf16 A2b (gather g2)
// OR fp32 A2f (KS%32==0 required; loads issued at stage, cvt+ds_write post-compute).
// Invalid chunks redirected to zbuf. B rows clamped so all staging passes are full
// (uniform vmcnt). Bias preloaded + pinned so no stray VMEM breaks the count.
template<int NT>
__global__ __launch_bounds__(256) void mm_tile(
    const bf16* __restrict__ A1, int lda1, int kv1, const int* __restrict__ g1,
    int KS,
    const bf16* __restrict__ A2b, int lda2b, int kv2b, const int* __restrict__ g2,
    const float* __restrict__ A2f, int lda2f, int kv2f,
    const bf16* __restrict__ WT, int kpad,
    const bf16* __restrict__ zbuf,
    const float* __restrict__ bias,
    bf16* __restrict__ C, int ldc,
    int M, int nvalid, int act)
{
  constexpr int BN = NT*16;
  constexpr int BPASS = (BN*4 + 255)/256;   // full B staging passes (clamped rows)
  constexpr int ABYTES = 8192;              // 128 rows x 64 B
  constexpr int BUFSZ = ABYTES + BPASS*4096;
  __shared__ __align__(16) char lds[3*BUFSZ];

  const int tid  = threadIdx.x;
  const int wave = tid>>6, lane = tid&63;
  const int quad = lane>>4, lo = lane&15;
  const int nstrip = blockIdx.y;
  WT += (size_t)nstrip*BN*kpad;
  C  += (size_t)nstrip*BN;
  if(bias) bias += nstrip*BN;
  const int nval = nvalid - nstrip*BN;
  const int row0 = blockIdx.x*128;

  // ---- bias preload (pinned: keeps VMEM count in the loop exact) ----
  float bvr[NT];
#pragma unroll
  for(int n=0;n<NT;n++){
    int col = n*16 + lo;
    bvr[n] = (bias && col < nval) ? bias[col] : 0.f;
  }
#pragma unroll
  for(int n=0;n<NT;n++) asm volatile("" :: "v"(bvr[n]));

  // ---- staging address precompute ----
  const char*  a1b[2];
  const char*  a2b[2];
  const float* f2base[2];
  int acol0[2];
#pragma unroll
  for(int p=0;p<2;p++){
    int s = p*256 + tid;
    int row = s>>2, cp = s&3;
    int q = cp ^ ((row>>1)&3);
    int col0 = q*8;
    int rg = row0 + row; if(rg > M-1) rg = M-1;
    int r1 = g1 ? g1[rg] : rg;
    int r2 = g2 ? g2[rg] : rg;
    acol0[p] = col0;
    a1b[p]   = (const char*)A1 + ((size_t)r1*lda1 + col0)*2;
    a2b[p]   = A2b ? (const char*)A2b + ((size_t)r2*lda2b)*2 : nullptr;
    f2base[p]= A2f ? (A2f + (size_t)rg*lda2f) : nullptr;
  }
  const char* bbase[BPASS];
#pragma unroll
  for(int p=0;p<BPASS;p++){
    int s = p*256 + tid;
    int rb = s>>2; if(rb > BN-1) rb = BN-1;   // clamp: full pass, dup rows land in pad
    int cp = s&3;
    int lq = cp ^ ((rb>>1)&3);
    bbase[p] = (const char*)WT + ((size_t)rb*kpad + lq*8)*2;
  }

  f32x4 acc[2][NT];
#pragma unroll
  for(int m=0;m<2;m++)
#pragma unroll
    for(int n=0;n<NT;n++) acc[m][n] = (f32x4){0.f,0.f,0.f,0.f};

  float4 pf0[2], pf1[2];

  auto stageA1 = [&](char* buf, int kb){
#pragma unroll
    for(int p=0;p<2;p++){
      int k = kb + acol0[p];
      const char* s;
      if(k < KS) s = (k < kv1) ? (a1b[p] + (size_t)kb*2) : (const char*)zbuf;
      else { int o = k - KS; s = (o < kv2b) ? (a2b[p] + (size_t)o*2) : (const char*)zbuf; }
      gload_lds16(s, buf + p*4096 + wave*1024);
    }
  };
  auto loadA2f = [&](int kb){
#pragma unroll
    for(int p=0;p<2;p++){
      int o = kb + acol0[p] - KS;
      const float* ap = f2base[p] + o;
      pf0[p] = (o   < kv2f) ? *(const float4*)ap     : (float4){0.f,0.f,0.f,0.f};
      pf1[p] = (o+4 < kv2f) ? *(const float4*)(ap+4) : (float4){0.f,0.f,0.f,0.f};
    }
  };
  auto writeA2 = [&](char* buf){
#pragma unroll
    for(int p=0;p<2;p++){
      s16x8 v;
      v[0]=f2s(pf0[p].x); v[1]=f2s(pf0[p].y); v[2]=f2s(pf0[p].z); v[3]=f2s(pf0[p].w);
      v[4]=f2s(pf1[p].x); v[5]=f2s(pf1[p].y); v[6]=f2s(pf1[p].z); v[7]=f2s(pf1[p].w);
      *(s16x8*)(buf + p*4096 + (size_t)tid*16) = v;
    }
  };
  auto stageB = [&](char* buf, int kb){
#pragma unroll
    for(int p=0;p<BPASS;p++)
      gload_lds16(bbase[p] + (size_t)kb*2, buf + ABYTES + p*4096 + wave*1024);
  };
  auto compute = [&](const char* buf){
    s16x8 af[2];
#pragma unroll
    for(int m=0;m<2;m++){
      int rl = wave*32 + m*16 + lo;
      int cp = quad ^ ((rl>>1)&3);
      af[m] = *(const s16x8*)(buf + rl*64 + cp*16);
    }
#pragma unroll
    for(int n=0;n<NT;n++){
      int rb = n*16 + lo;
      int cp = quad ^ ((rb>>1)&3);
      s16x8 bfr = *(const s16x8*)(buf + ABYTES + rb*64 + cp*16);
      acc[0][n] = __builtin_amdgcn_mfma_f32_16x16x32_bf16(af[0], bfr, acc[0][n], 0,0,0);
      acc[1][n] = __builtin_amdgcn_mfma_f32_16x16x32_bf16(af[1], bfr, acc[1][n], 0,0,0);
    }
  };

  const int T = kpad >> 5;
  // prologue: tiles 0,1 (always bf16-region: KS>=64 whenever A2f is used)
  stageA1(lds, 0); stageB(lds, 0);
  if(T > 1){ stageA1(lds + BUFSZ, 32); stageB(lds + BUFSZ, 32); }

  for(int t=0; t<T; t++){
    bool nb  = (t+1 < T);
    bool nfp = nb && A2f && (((t+1)<<5) >= KS);
    if(!nb)      wait_vmcnt<0>();
    else if(nfp) wait_vmcnt<BPASS>();      // fp32 tile's floats already drained
    else         wait_vmcnt<2+BPASS>();
    wait_lgkm0();
    __builtin_amdgcn_s_barrier();
    memfence();
    int tp = t+2;
    bool sp  = (tp < T);
    bool spf = sp && A2f && ((tp<<5) >= KS);
    char* nb3 = lds + (tp%3)*BUFSZ;
    if(sp){
      int kb2 = tp<<5;
      if(spf) loadA2f(kb2);
      else    stageA1(nb3, kb2);
      stageB(nb3, kb2);
    }
    compute(lds + (t%3)*BUFSZ);
    if(spf) writeA2(nb3);   // auto vmcnt wait on the float loads; B gloads stay in flight
  }

  // ---- epilogue: bias + act, lane-pair pack, b32 stores ----
  const int r0 = (lane&1)<<1;
#pragma unroll
  for(int n=0;n<NT;n++){
    int col  = n*16 + lo;
    int pcol = col & ~1;
    bool cok = (pcol < nval);
    float bv = bvr[n];
#pragma unroll
    for(int m=0;m<2;m++){
      float v[4];
#pragma unroll
      for(int r=0;r<4;r++){
        float t = acc[m][n][r] + bv;
        if(act==1) t = fmaxf(t, 0.f);
        else if(act==2) t = fast_tanh(t);
        v[r] = t;
      }
      unsigned mylo = (unsigned)(unsigned short)f2s(v[r0])
                    | ((unsigned)(unsigned short)f2s(v[r0+1])<<16);
      unsigned snd  = (unsigned)(unsigned short)f2s(v[r0^2])
                    | ((unsigned)(unsigned short)f2s(v[(r0^2)+1])<<16);
      unsigned got  = (unsigned)__shfl_xor((int)snd, 1);
      unsigned w0, w1;
      if(lane&1){ w0 = (got & 0xffffu) | (mylo<<16); w1 = (got>>16) | (mylo & 0xffff0000u); }
      else      { w0 = (mylo & 0xffffu) | (got<<16); w1 = (mylo>>16) | (got & 0xffff0000u); }
      if(cok){
        int prow = row0 + wave*32 + m*16 + quad*4 + r0;
        if(prow   < M) *(unsigned*)(C + (size_t)prow*ldc + pcol) = w0;
        if(prow+1 < M) *(unsigned*)(C + (size_t)(prow+1)*ldc + pcol) = w1;
      }
    }
  }
}

// ------ fused attention: one wave per node; online softmax; skip-add + relu ------
__global__ __launch_bounds__(256) void k_attn(
    const int* __restrict__ rowptr, const int* __restrict__ elist,
    const int* __restrict__ srcv,
    const bf16* __restrict__ qkvs, const bf16* __restrict__ eh,
    bf16* __restrict__ hout, int ldh, int colofs, int zpad)
{
  int wave = threadIdx.x>>6, lane = threadIdx.x&63;
  int node = blockIdx.x*4 + wave;
  if(node >= NN) return;
  bool act = (lane < 50);
  float q0=0.f, q1=0.f;
  const unsigned* qrow = (const unsigned*)(qkvs + (size_t)node*400);
  if(act){ unsigned u = qrow[lane]; q0=u2f_lo(u); q1=u2f_hi(u); }
  int s0 = rowptr[node], s1 = rowptr[node+1];
  float m = -3.4e38f, d = 0.f, a0 = 0.f, a1 = 0.f;
  for(int j=s0; j<s1; j++){
    int e = elist[j];
    int sn = srcv[e];
    float p = 0.f, e0=0.f, e1=0.f;
    if(act){
      unsigned uk = ((const unsigned*)(qkvs + (size_t)sn*400 + 100))[lane];
      unsigned ue = ((const unsigned*)(eh   + (size_t)e*100))[lane];
      e0=u2f_lo(ue); e1=u2f_hi(ue);
      p = q0*(u2f_lo(uk)+e0) + q1*(u2f_hi(uk)+e1);
    }
    for(int off=32; off; off>>=1) p += __shfl_xor(p, off);
    float alpha = p * 0.1f;
    float mn = fmaxf(m, alpha);
    float sc = __expf(m - mn);
    float wv = __expf(alpha - mn);
    d = d*sc + wv;
    if(act){
      unsigned uv = ((const unsigned*)(qkvs + (size_t)sn*400 + 200))[lane];
      a0 = a0*sc + wv*(u2f_lo(uv)+e0);
      a1 = a1*sc + wv*(u2f_hi(uv)+e1);
    }
    m = mn;
  }
  if(act){
    float inv = 1.f/(d + 1e-16f);
    unsigned us = ((const unsigned*)(qkvs + (size_t)node*400 + 300))[lane];
    float h0 = fmaxf(u2f_lo(us) + a0*inv, 0.f);
    float h1 = fmaxf(u2f_hi(us) + a1*inv, 0.f);
    bf16* op = hout + (size_t)node*ldh + colofs + lane*2;
    op[0] = f2b(h0); op[1] = f2b(h1);
  } else if(zpad && lane < 56){
    bf16* op = hout + (size_t)node*ldh + colofs + lane*2;
    op[0] = f2b(0.f); op[1] = f2b(0.f);
  }
}

// ------ linkpred final layer: out[e] = t3[e] @ w4 + b4 (K=50, N=2, fp32) ------
__global__ void k_lpout(const bf16* __restrict__ t3, const float* __restrict__ w4,
                        const float* __restrict__ b4, float* __restrict__ out,
                        int base, int n){
  int i = blockIdx.x*blockDim.x + threadIdx.x;
  if(i >= n*2) return;
  int g = i>>1, j = i&1;
  const bf16* tp = t3 + (size_t)g*50;
  float s = 0.f;
  for(int k=0;k<50;k++) s += b2f(tp[k])*w4[k*2+j];
  out[(size_t)(base+g)*2 + j] = s + b4[j];
}

extern "C" void kernel_launch(void* const* d_in, const int* in_sizes, int n_in,
                              void* d_out, int out_size, void* d_ws, size_t ws_size,
                              hipStream_t stream){
  const float* x       = (const float*)d_in[0];
  const float* msg     = (const float*)d_in[1];
  const float* time_w  = (const float*)d_in[2];
  const float* time_b  = (const float*)d_in[3];
  const float* c1_qw=(const float*)d_in[4];  const float* c1_qb=(const float*)d_in[5];
  const float* c1_kw=(const float*)d_in[6];  const float* c1_kb=(const float*)d_in[7];
  const float* c1_vw=(const float*)d_in[8];  const float* c1_vb=(const float*)d_in[9];
  const float* c1_ew=(const float*)d_in[10];
  const float* c1_sw=(const float*)d_in[11]; const float* c1_sb=(const float*)d_in[12];
  const float* c2_qw=(const float*)d_in[13]; const float* c2_qb=(const float*)d_in[14];
  const float* c2_kw=(const float*)d_in[15]; const float* c2_kb=(const float*)d_in[16];
  const float* c2_vw=(const float*)d_in[17]; const float* c2_vb=(const float*)d_in[18];
  const float* c2_ew=(const float*)d_in[19];
  const float* c2_sw=(const float*)d_in[20]; const float* c2_sb=(const float*)d_in[21];
  const float* lp_src_w=(const float*)d_in[22]; const float* lp_src_b=(const float*)d_in[23];
  const float* lp_dst_w=(const float*)d_in[24]; const float* lp_dst_b=(const float*)d_in[25];
  const float* lp1_w=(const float*)d_in[26]; const float* lp1_b=(const float*)d_in[27];
  const float* lp2_w=(const float*)d_in[28]; const float* lp2_b=(const float*)d_in[29];
  const float* lp3_w=(const float*)d_in[30]; const float* lp3_b=(const float*)d_in[31];
  const float* lp4_w=(const float*)d_in[32]; const float* lp4_b=(const float*)d_in[33];
  const int* last_update=(const int*)d_in[34];
  const int* tt =(const int*)d_in[35];
  const int* edge_index=(const int*)d_in[36];
  const int* src = edge_index;
  const int* dst = edge_index + EE;
  float* out = (float*)d_out;

  // ---- workspace (peak ~199.72 MB, < proved-safe 201.8 MB) ----
  char* ws = (char*)d_ws;
  bf16*  h1    = (bf16*) (ws + 0);             // N*800 bf16 = 80,000,000
  bf16*  relpad= (bf16*) (ws + 80000000);      // E*112 bf16 = 33,600,000
  bf16*  eh    = (bf16*) (ws + 113600000);     // E*100 bf16 = 30,000,000
  bf16*  qkvs  = (bf16*) (ws + 143600000);     // N*400 bf16 = 40,000,000
  bf16*  h2p   = (bf16*) (ws + 183600000);     // N*112 bf16 = 11,200,000
  bf16*  xb    = (bf16*) (ws + 183600000);     // overlay: xb dead before h2p written
  int*   rowptr= (int*)  (ws + 194800000);     // N+1
  int*   elist = (int*)  (ws + 195000064);     // E
  int*   deg   = (int*)  (ws + 195600064);     // N
  int*   cursor= (int*)  (ws + 195800064);     // N
  bf16* c1all  = (bf16*)(ws + 196000064);  // 8 x [448][128]
  bf16* c1eall = (bf16*)(ws + 196917568);  // 8 x [112][256]
  bf16* c2all  = (bf16*)(ws + 197376320);  // [448][800] (<= slot)
  bf16* c2e    = (bf16*)(ws + 198179136);  // [112][256]
  bf16* lp1tF  = (bf16*)(ws + 198351168);  // [800][224] folded U|V
  bf16* lp2t   = (bf16*)(ws + 199268672);  // [224][800]
  bf16* lp3t   = (bf16*)(ws + 199670080);  // [64][224]
  float* c1ball= (float*)(ws + 199702848); // [8][400]
  float* c2ball= (float*)(ws + 199715648); // [400]
  bf16* zbuf   = (bf16*)(ws + 199717248);  // 64 B zeros
  float* lp1c  = (float*)(ws + 199717312); // [800] folded bias -> ends 199,720,512
  // linkpred-phase overlays (conv buffers 0..183.6MB dead):
  bf16* lt1 = (bf16*)(ws + 0);             // EH*800 bf16 = 120 MB
  bf16* lt2 = (bf16*)(ws + 120000000);     // EH*200 bf16 = 30 MB
  bf16* lt3 = (bf16*)(ws + 150000000);     // EH*50  bf16 = 7.5 MB

  // ---- weight conversion / folds ----
  k_wtc1<<<(8*448*128+255)/256,256,0,stream>>>(c1_qw,c1_kw,c1_vw,c1_sw,c1all);
  for(int h=0; h<8; h++)
    k_wte<<<(112*256+255)/256,256,0,stream>>>(c1_ew, 800, h*100, c1eall + (size_t)h*112*256);
  k_wte<<<(112*256+255)/256,256,0,stream>>>(c2_ew, 100, 0, c2e);
  k_wt2<<<(100*800+255)/256,256,0,stream>>>(c2_qw,800,100,0,100,c2all,         800,100);
  k_wt2<<<(100*800+255)/256,256,0,stream>>>(c2_kw,800,100,0,100,c2all+100*800, 800,100);
  k_wt2<<<(100*800+255)/256,256,0,stream>>>(c2_vw,800,100,0,100,c2all+200*800, 800,100);
  k_wt2<<<(100*800+255)/256,256,0,stream>>>(c2_sw,800,100,0,100,c2all+300*800, 800,100);
  k_wt2<<<(48*800+255)/256,256,0,stream>>>(c2_sw,800,100,0,0,   c2all+400*800, 800,48);
  k_wt2<<<(224*800+255)/256,256,0,stream>>>(lp2_w,800,200,0,200,lp2t,800,224);
  k_wt2<<<(64*224+255)/256,256,0,stream>>>(lp3_w,200,50,0,50,lp3t,224,64);
  k_foldw<<<(800*224+255)/256,256,0,stream>>>(lp_src_w, lp_dst_w, lp1_w, lp1tF);
  k_foldb<<<(800+255)/256,256,0,stream>>>(lp_src_b, lp_dst_b, lp1_w, lp1_b, lp1c);
  k_bstack<<<(3200+255)/256,256,0,stream>>>(c1_qb,c1_kb,c1_vb,c1_sb,100,8,c1ball);
  k_bstack<<<(400+255)/256,256,0,stream>>>(c2_qb,c2_kb,c2_vb,c2_sb,100,1,c2ball);
  k_zero<<<1,64,0,stream>>>((int*)zbuf, 16);
  k_cvtpad<<<(NN*112+255)/256,256,0,stream>>>(x, 100, xb, 112, NN*112);

  // ---- CSR build ----
  k_zero   <<<(NN+255)/256, 256, 0, stream>>>(deg, NN);
  k_zero   <<<(NN+255)/256, 256, 0, stream>>>(cursor, NN);
  k_hist   <<<(EE+255)/256, 256, 0, stream>>>(dst, deg);
  k_scan   <<<1, 1024, 0, stream>>>(deg, rowptr);
  k_scatter<<<(EE+255)/256, 256, 0, stream>>>(dst, rowptr, cursor, elist);

  // ---- time encoding ----
  k_relenc<<<(EE*112+255)/256, 256, 0, stream>>>(src, tt, last_update, time_w, time_b, relpad);

  int gN = (NN + 127)/128;   // 391
  int gE = (EE + 127)/128;   // 1172
  int gL = (EH + 127)/128;   // 586
  int gA = (NN + 3)/4;

  // ---- conv1: per head = node GEMM (3 strips of 144) + edge GEMM + attention ----
  for(int h=0; h<8; h++){
    mm_tile<9><<<dim3(gN,3),256,0,stream>>>(xb,112,112,nullptr, 128,
        nullptr,0,0,nullptr, nullptr,0,0,
        c1all + (size_t)h*448*128, 128, zbuf, c1ball + h*400, qkvs,400, NN,400,0);
    mm_tile<7><<<dim3(gE,1),256,0,stream>>>(relpad,112,112,nullptr, 128,
        nullptr,0,0,nullptr, msg,100,100,
        c1eall + (size_t)h*112*256, 256, zbuf, nullptr, eh,100, EE,100,0);
    k_attn<<<gA,256,0,stream>>>(rowptr, elist, src, qkvs, eh, h1, 800, h*100, 0);
  }

  // ---- conv2 (h2 written 112-padded, pad cols zeroed) ----
  mm_tile<9><<<dim3(gN,3),256,0,stream>>>(h1,800,800,nullptr, 800,
      nullptr,0,0,nullptr, nullptr,0,0,
      c2all,800, zbuf, c2ball, qkvs,400, NN,400,0);
  mm_tile<7><<<dim3(gE,1),256,0,stream>>>(relpad,112,112,nullptr, 128,
      nullptr,0,0,nullptr, msg,100,100,
      c2e,256, zbuf, nullptr, eh,100, EE,100,0);
  k_attn<<<gA,256,0,stream>>>(rowptr, elist, src, qkvs, eh, h2p, 112, 0, 1);

  // ---- link predictor (hh folded into t1): 2 edge-halves ----
  for(int half=0; half<2; half++){
    const int* esrc = src + half*EH;
    const int* edst = dst + half*EH;
    // t1 = tanh(h_src@U + h_dst@V + c): dual-gather, K=224, N=800 (5 strips of 160)
    mm_tile<10><<<dim3(gL,5),256,0,stream>>>(h2p,112,112,esrc, 112,
        h2p,112,112,edst, nullptr,0,0,
        lp1tF,224, zbuf, lp1c, lt1,800, EH,800,2);
    // t2 = tanh(t1@W2+b2): K=800, N=200 (2 strips of 112)
    mm_tile<7><<<dim3(gL,2),256,0,stream>>>(lt1,800,800,nullptr, 800,
        nullptr,0,0,nullptr, nullptr,0,0,
        lp2t,800, zbuf, lp2_b, lt2,200, EH,200,2);
    // t3 = tanh(t2@W3+b3): K=200(224), N=50
    mm_tile<4><<<dim3(gL,1),256,0,stream>>>(lt2,200,200,nullptr, 224,
        nullptr,0,0,nullptr, nullptr,0,0,
        lp3t,224, zbuf, lp3_b, lt3,50, EH,50,2);
    // out = t3@W4+b4
    k_lpout<<<(EH*2+255)/256,256,0,stream>>>(lt3, lp4_w, lp4_b, out, half*EH, EH);
  }

  (void)in_sizes; (void)n_in; (void)out_size; (void)ws_size;
}